// Round 9
// baseline (380.889 us; speedup 1.0000x reference)
//
#include <hip/hip_runtime.h>
#include <stdint.h>

typedef unsigned short u16;
typedef __attribute__((ext_vector_type(8))) short short8;   // 8 x bf16 (4 VGPRs)
typedef __attribute__((ext_vector_type(4))) short s16x4;    // 4 x bf16 (2 VGPRs)
typedef __attribute__((ext_vector_type(4))) float floatx4;  // MFMA 16x16 C/D

__device__ __forceinline__ u16 f2bf(float f) {
  union { float f; unsigned u; } v; v.f = f;
  return (u16)((v.u + 0x7FFFu + ((v.u >> 16) & 1u)) >> 16);  // RNE
}
__device__ __forceinline__ void gl_lds16(const void* g, void* l) {
  __builtin_amdgcn_global_load_lds((const __attribute__((address_space(1))) void*)g,
                                   (__attribute__((address_space(3))) void*)l, 16, 0, 0);
}
__device__ __forceinline__ float exp2_fast(float x) {
#if __has_builtin(__builtin_amdgcn_exp2f)
  return __builtin_amdgcn_exp2f(x);
#else
  return exp2f(x);
#endif
}

// ---------------- prep: cast x (fp32 -> bf16), 8 elems/thread ----------------
__global__ __launch_bounds__(256) void k_cast_x(const float* __restrict__ x, u16* __restrict__ xb) {
  int t = blockIdx.x * 256 + threadIdx.x;
  const float4* xv = (const float4*)x;
  float4 a = xv[2 * t], b = xv[2 * t + 1];
  short8 o;
  o[0] = f2bf(a.x); o[1] = f2bf(a.y); o[2] = f2bf(a.z); o[3] = f2bf(a.w);
  o[4] = f2bf(b.x); o[5] = f2bf(b.y); o[6] = f2bf(b.z); o[7] = f2bf(b.w);
  ((short8*)xb)[t] = o;
}

// ------------- prep: transpose+cast w_qkv [512,1536] and w_out [512,512] -----
__global__ __launch_bounds__(256) void k_prep_w(const float* __restrict__ wqkv, const float* __restrict__ wout,
                                                u16* __restrict__ wqkvT, u16* __restrict__ woutT) {
  int t = blockIdx.x * 256 + threadIdx.x;
  if (t < 786432) {
    int n = t >> 9, k = t & 511;
    wqkvT[t] = f2bf(wqkv[k * 1536 + n]);
  } else {
    int u = t - 786432;
    int n = u >> 9, k = u & 511;
    woutT[u] = f2bf(wout[k * 512 + n]);
  }
}

// ---- prep: bias pre-swizzled to swapped-QK lane order, (b-8)*log2e bf16 -----
// attn lane (quad,l15) of wave w, q-block ti owns qrow = qt*128+w*32+ti*16+l15
// and kcols kt64*64 + tjl*16 + quad*4 + r.  Layout (u16):
//   [h][qt][kt64 16][w][ti][lane 64][half 2][j 2][r 4]
// u16 addr = h*1048576 + qt*131072 + kt*8192 + w*2048 + ti*1024 + lane*16
//            + half*8 + j*4 + r,  tjl = half*2 + j.
__global__ __launch_bounds__(256) void k_prep_bias(const int* __restrict__ rel, const float* __restrict__ tab,
                                                   u16* __restrict__ biasb) {
  int t = blockIdx.x * 256 + threadIdx.x;   // 1,048,576 threads
  int half = t & 1;
  int lane = (t >> 1) & 63;
  int ti   = (t >> 7) & 1;
  int w    = (t >> 8) & 3;
  int kt   = (t >> 10) & 15;
  int qt   = (t >> 14) & 7;
  int h    = t >> 17;
  int l15 = lane & 15, quad = lane >> 4;
  int qrow = qt * 128 + w * 32 + ti * 16 + l15;
  const int* rr = rel + (size_t)qrow * 1024 + kt * 64 + quad * 4;
  short8 o;
  #pragma unroll
  for (int j = 0; j < 2; j++) {
    int tjl = half * 2 + j;
    int4 idx = *(const int4*)&rr[tjl * 16];
    o[j * 4 + 0] = f2bf((tab[idx.x * 8 + h] - 8.0f) * 1.44269504f);
    o[j * 4 + 1] = f2bf((tab[idx.y * 8 + h] - 8.0f) * 1.44269504f);
    o[j * 4 + 2] = f2bf((tab[idx.z * 8 + h] - 8.0f) * 1.44269504f);
    o[j * 4 + 3] = f2bf((tab[idx.w * 8 + h] - 8.0f) * 1.44269504f);
  }
  ((short8*)biasb)[t] = o;
}

// ---------------- GEMM1: qkv = xb @ wqkvT^T -> Q,K [b,h,n,d], V^T [b,h,d,n] --
__global__ __launch_bounds__(256) void k_gemm_qkv(const u16* __restrict__ xb, const u16* __restrict__ wT,
                                                  u16* __restrict__ qbuf, u16* __restrict__ kbuf,
                                                  u16* __restrict__ vtbuf) {
  __shared__ u16 sm[17408];
  const int bn = blockIdx.x, bm = blockIdx.y;
  const int tid = threadIdx.x, w = tid >> 6, lane = tid & 63;
  const int quad = lane >> 4, l15 = lane & 15;
  const int wr = w >> 1, wc = w & 1;
  const u16* Ag = xb + (size_t)bm * 128 * 512;
  const u16* Bg = wT + (size_t)bn * 128 * 512;
  floatx4 acc[4][4];
  floatx4 zero = {0.f, 0.f, 0.f, 0.f};
  #pragma unroll
  for (int i = 0; i < 4; i++)
    #pragma unroll
    for (int j = 0; j < 4; j++) acc[i][j] = zero;

  for (int kb = 0; kb < 512; kb += 32) {
    __syncthreads();
    #pragma unroll
    for (int i = 0; i < 2; i++) {
      int c = w * 128 + i * 64 + lane;
      int row = c >> 2, col = (c & 3) * 8;
      gl_lds16(Ag + (size_t)row * 512 + kb + col, &sm[(w * 128 + i * 64) * 8]);
      gl_lds16(Bg + (size_t)row * 512 + kb + col, &sm[4096 + (w * 128 + i * 64) * 8]);
    }
    __syncthreads();
    short8 af[4], bf[4];
    #pragma unroll
    for (int ti = 0; ti < 4; ti++)
      af[ti] = *(const short8*)&sm[(wr * 64 + ti * 16 + l15) * 32 + quad * 8];
    #pragma unroll
    for (int tj = 0; tj < 4; tj++)
      bf[tj] = *(const short8*)&sm[4096 + (wc * 64 + tj * 16 + l15) * 32 + quad * 8];
    #pragma unroll
    for (int ti = 0; ti < 4; ti++)
      #pragma unroll
      for (int tj = 0; tj < 4; tj++)
        acc[ti][tj] = __builtin_amdgcn_mfma_f32_16x16x32_bf16(af[ti], bf[tj], acc[ti][tj], 0, 0, 0);
  }
  __syncthreads();
  #pragma unroll
  for (int ti = 0; ti < 4; ti++)
    #pragma unroll
    for (int tj = 0; tj < 4; tj++)
      #pragma unroll
      for (int r = 0; r < 4; r++)
        sm[(wr * 64 + ti * 16 + quad * 4 + r) * 136 + wc * 64 + tj * 16 + l15] = f2bf(acc[ti][tj][r]);
  __syncthreads();
  const int b = bm >> 3;
  const int nrow0 = (bm & 7) * 128;
  if (bn < 8) {
    u16* dst = (bn < 4) ? qbuf : kbuf;
    #pragma unroll
    for (int i = 0; i < 8; i++) {
      int chunk = i * 256 + tid;
      int r = chunk >> 4, c8 = chunk & 15;
      int nin = (bn & 3) * 128 + c8 * 8;
      int h = nin >> 6, d = nin & 63;
      uint4 val = *(const uint4*)&sm[r * 136 + c8 * 8];
      *(uint4*)&dst[(((size_t)(b * 8 + h)) * 1024 + nrow0 + r) * 64 + d] = val;
    }
  } else {
    #pragma unroll
    for (int i = 0; i < 8; i++) {
      int chunk = i * 256 + tid;
      int dcol = chunk & 127, nr8 = chunk >> 7;
      int nin = (bn & 3) * 128 + dcol;
      int h = nin >> 6, d = nin & 63;
      short8 v;
      #pragma unroll
      for (int j = 0; j < 8; j++) v[j] = (short)sm[(nr8 * 8 + j) * 136 + dcol];
      *(short8*)&vtbuf[(((size_t)(b * 8 + h)) * 64 + d) * 1024 + nrow0 + nr8 * 8] = v;
    }
  }
}

// ---------------- flash attention v8: v6 structure + v4-proven cheap pack ----
// Only change vs v6 (verified, 145 us): P bf16 pack uses the v4-verified
// round-half-up `(bits + 0x8000) >> 16` (2 VALU ops/elem) instead of f2bf
// RNE (~4-5 ops/elem).  cvt_pk abandoned (R0/R8 both failed on it).
// Store stays s16x4; asm memory barrier before P reads retained.
// LDS (u16 idx): K0 [0,8192) V0 [8192,16384) K1 [16384,24576) V1 [24576,32768)
//                P [32768,40960)  (wave-private 32x64 per wave).
__global__ __launch_bounds__(256, 2) void k_attn(const u16* __restrict__ qbuf, const u16* __restrict__ kbuf,
                                                 const u16* __restrict__ vtbuf, const u16* __restrict__ biasb,
                                                 u16* __restrict__ attn_out) {
  __shared__ u16 sm[40960];
  const int PO = 32768;
  const int b = blockIdx.x, h = blockIdx.y >> 3, qt = blockIdx.y & 7;
  const int tid = threadIdx.x, w = tid >> 6, lane = tid & 63;
  const int quad = lane >> 4, l15 = lane & 15;
  const int xm = l15 & 7;
  const int qh = quad >> 1, ql = quad & 1;
  u16* pw = &sm[PO + w * 2048];                 // wave-private P: 32 rows x 64
  const size_t bh = (size_t)(b * 8 + h);
  const u16* qg = qbuf + (bh * 1024 + (size_t)qt * 128) * 64;
  const u16* kg = kbuf + bh * 1024 * 64;
  const u16* vg = vtbuf + bh * 64 * 1024;
  const u16* bg = biasb + (size_t)(h * 8 + qt) * 131072 + w * 2048 + lane * 16;

  // staging source indices (swizzled), loop-invariant (v4-identical)
  int rK[4], cK[4], dV[4], cV[4];
  #pragma unroll
  for (int i = 0; i < 4; i++) {
    int p = (w * 4 + i) * 64 + lane;
    rK[i] = p >> 3;  cK[i] = (p & 7) ^ (rK[i] & 7);
    dV[i] = p >> 4;  cV[i] = (p & 15) ^ (dV[i] & 7);
  }

  // Q fragments (MFMA B operand in swapped QK): once per block
  short8 qf[2][2];
  #pragma unroll
  for (int ti = 0; ti < 2; ti++)
    #pragma unroll
    for (int kk = 0; kk < 2; kk++)
      qf[ti][kk] = *(const short8*)&qg[(w * 32 + ti * 16 + l15) * 64 + kk * 32 + quad * 8];

  floatx4 oacc[2][4];
  floatx4 zero = {0.f, 0.f, 0.f, 0.f};
  #pragma unroll
  for (int i = 0; i < 2; i++)
    #pragma unroll
    for (int j = 0; j < 4; j++) oacc[i][j] = zero;
  float lrow[2] = {0.f, 0.f};   // partial row-sums, qrow = ti*16 + l15

  const float SC = 0.125f * 1.44269504f;

  // preload tile 0 into buffer 0 (v4-identical)
  #pragma unroll
  for (int i = 0; i < 4; i++) {
    gl_lds16(kg + (size_t)rK[i] * 64 + cK[i] * 8, &sm[(w * 4 + i) * 512]);
    gl_lds16(vg + (size_t)dV[i] * 1024 + cV[i] * 8, &sm[8192 + (w * 4 + i) * 512]);
  }
  __syncthreads();   // tile 0 resident

  for (int kt = 0; kt < 8; kt++) {
    const int cur = (kt & 1) ? 16384 : 0;
    const int nxt = (kt & 1) ? 0 : 16384;
    // prefetch kt+1 (v4-identical)
    if (kt < 7) {
      #pragma unroll
      for (int i = 0; i < 4; i++) {
        gl_lds16(kg + (size_t)((kt + 1) * 128 + rK[i]) * 64 + cK[i] * 8, &sm[nxt + (w * 4 + i) * 512]);
        gl_lds16(vg + (size_t)dV[i] * 1024 + (kt + 1) * 128 + cV[i] * 8, &sm[nxt + 8192 + (w * 4 + i) * 512]);
      }
    }

    #pragma unroll
    for (int tjh = 0; tjh < 2; tjh++) {
      // bias for this 64-col half (kt64 = kt*2 + tjh)
      const u16* bkt = bg + (kt * 2 + tjh) * 8192;
      const uint4 bA0 = *(const uint4*)&bkt[0];
      const uint4 bB0 = *(const uint4*)&bkt[8];
      const uint4 bA1 = *(const uint4*)&bkt[1024];
      const uint4 bB1 = *(const uint4*)&bkt[1024 + 8];

      // S^T = K Q^T for this 64-col half
      floatx4 sacc[2][4];
      #pragma unroll
      for (int tjl = 0; tjl < 4; tjl++) { sacc[0][tjl] = zero; sacc[1][tjl] = zero; }
      #pragma unroll
      for (int tjl = 0; tjl < 4; tjl++)
        #pragma unroll
        for (int kk = 0; kk < 2; kk++) {
          short8 kf = *(const short8*)&sm[cur + (tjh * 64 + tjl * 16 + l15) * 64 + ((kk * 4 + quad) ^ xm) * 8];
          sacc[0][tjl] = __builtin_amdgcn_mfma_f32_16x16x32_bf16(kf, qf[0][kk], sacc[0][tjl], 0, 0, 0);
          sacc[1][tjl] = __builtin_amdgcn_mfma_f32_16x16x32_bf16(kf, qf[1][kk], sacc[1][tjl], 0, 0, 0);
        }

      // softmax (static -8 shift, no max pass) + cheap half-up pack -> LDS
      #pragma unroll
      for (int ti = 0; ti < 2; ti++) {
        const uint4 bA = ti ? bA1 : bA0;
        const uint4 bB = ti ? bB1 : bB0;
        const int prow = (ti * 16 + l15) * 64;
        #pragma unroll
        for (int tjl = 0; tjl < 4; tjl++) {
          unsigned ulo = (tjl == 0) ? bA.x : (tjl == 1) ? bA.z : (tjl == 2) ? bB.x : bB.z;
          unsigned uhi = (tjl == 0) ? bA.y : (tjl == 1) ? bA.w : (tjl == 2) ? bB.y : bB.w;
          float b0 = __builtin_bit_cast(float, ulo << 16);
          float b1 = __builtin_bit_cast(float, ulo & 0xFFFF0000u);
          float b2 = __builtin_bit_cast(float, uhi << 16);
          float b3 = __builtin_bit_cast(float, uhi & 0xFFFF0000u);
          float p0 = exp2_fast(sacc[ti][tjl][0] * SC + b0);
          float p1 = exp2_fast(sacc[ti][tjl][1] * SC + b1);
          float p2 = exp2_fast(sacc[ti][tjl][2] * SC + b2);
          float p3 = exp2_fast(sacc[ti][tjl][3] * SC + b3);
          lrow[ti] += (p0 + p1) + (p2 + p3);
          s16x4 pv;
          pv[0] = (short)(u16)((__builtin_bit_cast(unsigned, p0) + 0x8000u) >> 16);
          pv[1] = (short)(u16)((__builtin_bit_cast(unsigned, p1) + 0x8000u) >> 16);
          pv[2] = (short)(u16)((__builtin_bit_cast(unsigned, p2) + 0x8000u) >> 16);
          pv[3] = (short)(u16)((__builtin_bit_cast(unsigned, p3) + 0x8000u) >> 16);
          *(s16x4*)&pw[prow + ((tjl * 2 + qh) ^ xm) * 8 + ql * 4] = pv;   // ds_write_b64
        }
      }
      // forbid compiler reordering of P reads before P writes (TBAA guard);
      // backend still inserts the lgkmcnt waits for the same-wave RAW.
      asm volatile("" ::: "memory");

      // O += P_half V_half   (V^T rows d=0..63, cols tjh*64 .. +63 of kt tile)
      #pragma unroll
      for (int kbl = 0; kbl < 2; kbl++) {
        const int gslP = ((kbl * 4 + quad) ^ xm) * 8;
        short8 pf0 = *(const short8*)&pw[l15 * 64 + gslP];
        short8 pf1 = *(const short8*)&pw[(16 + l15) * 64 + gslP];
        #pragma unroll
        for (int dj = 0; dj < 4; dj++) {
          int kc = (tjh * 8 + kbl * 4 + quad) ^ xm;   // V chunk (16 per row)
          short8 vf = *(const short8*)&sm[cur + 8192 + (dj * 16 + l15) * 128 + kc * 8];
          oacc[0][dj] = __builtin_amdgcn_mfma_f32_16x16x32_bf16(pf0, vf, oacc[0][dj], 0, 0, 0);
          oacc[1][dj] = __builtin_amdgcn_mfma_f32_16x16x32_bf16(pf1, vf, oacc[1][dj], 0, 0, 0);
        }
      }
    }
    __syncthreads();  // single barrier per kt: buffer handoff; vmcnt(0) drains
                      // a prefetch that aged through the whole compute phase
  }

  // epilogue: reduce row sums across quads, redistribute inv to O rows, store
  #pragma unroll
  for (int ti = 0; ti < 2; ti++) {
    float s = lrow[ti];
    s += __shfl_xor(s, 16);
    s += __shfl_xor(s, 32);
    float inv = 1.f / s;      // valid for qrow = ti*16 + l15
    #pragma unroll
    for (int r = 0; r < 4; r++) {
      float invr = __shfl(inv, (lane & 48) | (quad * 4 + r));  // inv of qrow quad*4+r
      int row = w * 32 + ti * 16 + quad * 4 + r;
      size_t ob = ((size_t)(b * 1024 + qt * 128 + row)) * 512 + h * 64;
      #pragma unroll
      for (int dj = 0; dj < 4; dj++)
        attn_out[ob + dj * 16 + l15] = f2bf(oacc[ti][dj][r] * invr);
    }
  }
}

// ---------------- GEMM3: out = attn @ w_out + b_out (fp32 out) ---------------
__global__ __launch_bounds__(256) void k_gemm_out(const u16* __restrict__ ab, const u16* __restrict__ wT,
                                                  const float* __restrict__ bout, float* __restrict__ out) {
  __shared__ u16 sm[8192];
  const int bn = blockIdx.x, bm = blockIdx.y;
  const int tid = threadIdx.x, w = tid >> 6, lane = tid & 63;
  const int quad = lane >> 4, l15 = lane & 15;
  const int wr = w >> 1, wc = w & 1;
  const u16* Ag = ab + (size_t)bm * 128 * 512;
  const u16* Bg = wT + (size_t)bn * 128 * 512;
  float bv[4];
  #pragma unroll
  for (int tj = 0; tj < 4; tj++) bv[tj] = bout[bn * 128 + wc * 64 + tj * 16 + l15];
  floatx4 acc[4][4];
  floatx4 zero = {0.f, 0.f, 0.f, 0.f};
  #pragma unroll
  for (int i = 0; i < 4; i++)
    #pragma unroll
    for (int j = 0; j < 4; j++) acc[i][j] = zero;

  for (int kb = 0; kb < 512; kb += 32) {
    __syncthreads();
    #pragma unroll
    for (int i = 0; i < 2; i++) {
      int c = w * 128 + i * 64 + lane;
      int row = c >> 2, col = (c & 3) * 8;
      gl_lds16(Ag + (size_t)row * 512 + kb + col, &sm[(w * 128 + i * 64) * 8]);
      gl_lds16(Bg + (size_t)row * 512 + kb + col, &sm[4096 + (w * 128 + i * 64) * 8]);
    }
    __syncthreads();
    short8 af[4], bf[4];
    #pragma unroll
    for (int ti = 0; ti < 4; ti++)
      af[ti] = *(const short8*)&sm[(wr * 64 + ti * 16 + l15) * 32 + quad * 8];
    #pragma unroll
    for (int tj = 0; tj < 4; tj++)
      bf[tj] = *(const short8*)&sm[4096 + (wc * 64 + tj * 16 + l15) * 32 + quad * 8];
    #pragma unroll
    for (int ti = 0; ti < 4; ti++)
      #pragma unroll
      for (int tj = 0; tj < 4; tj++)
        acc[ti][tj] = __builtin_amdgcn_mfma_f32_16x16x32_bf16(af[ti], bf[tj], acc[ti][tj], 0, 0, 0);
  }
  #pragma unroll
  for (int ti = 0; ti < 4; ti++)
    #pragma unroll
    for (int tj = 0; tj < 4; tj++)
      #pragma unroll
      for (int r = 0; r < 4; r++) {
        int row = bm * 128 + wr * 64 + ti * 16 + quad * 4 + r;
        int colg = bn * 128 + wc * 64 + tj * 16 + l15;
        out[(size_t)row * 512 + colg] = acc[ti][tj][r] + bv[tj];
      }
}

// ---------------- launch -----------------------------------------------------
extern "C" void kernel_launch(void* const* d_in, const int* in_sizes, int n_in,
                              void* d_out, int out_size, void* d_ws, size_t ws_size,
                              hipStream_t stream) {
  const float* x    = (const float*)d_in[0];
  const float* wqkv = (const float*)d_in[1];
  const float* wout = (const float*)d_in[2];
  const float* bout = (const float*)d_in[3];
  const float* btab = (const float*)d_in[4];
  const int*   rel  = (const int*)d_in[5];
  char* ws = (char*)d_ws;
  u16* xb    = (u16*)(ws + 0);           // x bf16, reused as attn_out
  u16* qbuf  = (u16*)(ws + 33554432);
  u16* kbuf  = (u16*)(ws + 67108864);
  u16* vtbuf = (u16*)(ws + 100663296);
  u16* biasb = (u16*)(ws + 134217728);
  u16* wqkvT = (u16*)(ws + 150994944);
  u16* woutT = (u16*)(ws + 152567808);
  float* out = (float*)d_out;

  k_cast_x  <<<8192, 256, 0, stream>>>(x, xb);
  k_prep_w  <<<4096, 256, 0, stream>>>(wqkv, wout, wqkvT, woutT);
  k_prep_bias<<<4096, 256, 0, stream>>>(rel, btab, biasb);
  k_gemm_qkv<<<dim3(12, 256), 256, 0, stream>>>(xb, wqkvT, qbuf, kbuf, vtbuf);
  k_attn    <<<dim3(32, 64), 256, 0, stream>>>(qbuf, kbuf, vtbuf, biasb, xb);
  k_gemm_out<<<dim3(4, 256), 256, 0, stream>>>(xb, woutT, bout, out);
}

// Round 10
// 366.732 us; speedup vs baseline: 1.0386x; 1.0386x over previous
//
#include <hip/hip_runtime.h>
#include <stdint.h>

typedef unsigned short u16;
typedef __attribute__((ext_vector_type(8))) short short8;   // 8 x bf16 (4 VGPRs)
typedef __attribute__((ext_vector_type(4))) short s16x4;    // 4 x bf16 (2 VGPRs)
typedef __attribute__((ext_vector_type(4))) float floatx4;  // MFMA 16x16 C/D

__device__ __forceinline__ u16 f2bf(float f) {
  union { float f; unsigned u; } v; v.f = f;
  return (u16)((v.u + 0x7FFFu + ((v.u >> 16) & 1u)) >> 16);  // RNE
}
__device__ __forceinline__ void gl_lds16(const void* g, void* l) {
  __builtin_amdgcn_global_load_lds((const __attribute__((address_space(1))) void*)g,
                                   (__attribute__((address_space(3))) void*)l, 16, 0, 0);
}
__device__ __forceinline__ float exp2_fast(float x) {
#if __has_builtin(__builtin_amdgcn_exp2f)
  return __builtin_amdgcn_exp2f(x);
#else
  return exp2f(x);
#endif
}

// ---------------- fused prep: cast x (blocks 0..8191) | transpose w (8192..) -
__global__ __launch_bounds__(256) void k_prep(const float* __restrict__ x, u16* __restrict__ xb,
                                              const float* __restrict__ wqkv, const float* __restrict__ wout,
                                              u16* __restrict__ wqkvT, u16* __restrict__ woutT) {
  int bid = blockIdx.x;
  if (bid < 8192) {
    int t = bid * 256 + threadIdx.x;
    const float4* xv = (const float4*)x;
    float4 a = xv[2 * t], b = xv[2 * t + 1];
    short8 o;
    o[0] = f2bf(a.x); o[1] = f2bf(a.y); o[2] = f2bf(a.z); o[3] = f2bf(a.w);
    o[4] = f2bf(b.x); o[5] = f2bf(b.y); o[6] = f2bf(b.z); o[7] = f2bf(b.w);
    ((short8*)xb)[t] = o;
  } else {
    int t = (bid - 8192) * 256 + threadIdx.x;
    if (t < 786432) {
      int n = t >> 9, k = t & 511;
      wqkvT[t] = f2bf(wqkv[k * 1536 + n]);
    } else {
      int u = t - 786432;
      int n = u >> 9, k = u & 511;
      woutT[u] = f2bf(wout[k * 512 + n]);
    }
  }
}

// ------ fused GEMM1 (blocks 0..3071) | bias prep (blocks 3072..7167) ---------
// GEMM1: qkv = xb @ wqkvT^T -> Q,K [b,h,n,d], V^T [b,h,d,n].  bn=id%12 keeps
// the original x-fastest dispatch order.  Bias prep is independent gather
// work (latency-bound, no LDS use) co-resident with the GEMM to fill its
// memory-wait bubbles.  Bias layout (verified v6/v8):
//   [h][qt][kt64 16][w][ti][lane 64][half 2][j 2][r 4]
__global__ __launch_bounds__(256) void k_gemm_qkv_bias(const u16* __restrict__ xb, const u16* __restrict__ wT,
                                                       u16* __restrict__ qbuf, u16* __restrict__ kbuf,
                                                       u16* __restrict__ vtbuf,
                                                       const int* __restrict__ rel, const float* __restrict__ tab,
                                                       u16* __restrict__ biasb) {
  __shared__ u16 sm[17408];
  const int bid = blockIdx.x;
  if (bid < 3072) {
    const int bn = bid % 12, bm = bid / 12;
    const int tid = threadIdx.x, w = tid >> 6, lane = tid & 63;
    const int quad = lane >> 4, l15 = lane & 15;
    const int wr = w >> 1, wc = w & 1;
    const u16* Ag = xb + (size_t)bm * 128 * 512;
    const u16* Bg = wT + (size_t)bn * 128 * 512;
    floatx4 acc[4][4];
    floatx4 zero = {0.f, 0.f, 0.f, 0.f};
    #pragma unroll
    for (int i = 0; i < 4; i++)
      #pragma unroll
      for (int j = 0; j < 4; j++) acc[i][j] = zero;

    for (int kb = 0; kb < 512; kb += 32) {
      __syncthreads();
      #pragma unroll
      for (int i = 0; i < 2; i++) {
        int c = w * 128 + i * 64 + lane;
        int row = c >> 2, col = (c & 3) * 8;
        gl_lds16(Ag + (size_t)row * 512 + kb + col, &sm[(w * 128 + i * 64) * 8]);
        gl_lds16(Bg + (size_t)row * 512 + kb + col, &sm[4096 + (w * 128 + i * 64) * 8]);
      }
      __syncthreads();
      short8 af[4], bf[4];
      #pragma unroll
      for (int ti = 0; ti < 4; ti++)
        af[ti] = *(const short8*)&sm[(wr * 64 + ti * 16 + l15) * 32 + quad * 8];
      #pragma unroll
      for (int tj = 0; tj < 4; tj++)
        bf[tj] = *(const short8*)&sm[4096 + (wc * 64 + tj * 16 + l15) * 32 + quad * 8];
      #pragma unroll
      for (int ti = 0; ti < 4; ti++)
        #pragma unroll
        for (int tj = 0; tj < 4; tj++)
          acc[ti][tj] = __builtin_amdgcn_mfma_f32_16x16x32_bf16(af[ti], bf[tj], acc[ti][tj], 0, 0, 0);
    }
    __syncthreads();
    #pragma unroll
    for (int ti = 0; ti < 4; ti++)
      #pragma unroll
      for (int tj = 0; tj < 4; tj++)
        #pragma unroll
        for (int r = 0; r < 4; r++)
          sm[(wr * 64 + ti * 16 + quad * 4 + r) * 136 + wc * 64 + tj * 16 + l15] = f2bf(acc[ti][tj][r]);
    __syncthreads();
    const int b = bm >> 3;
    const int nrow0 = (bm & 7) * 128;
    if (bn < 8) {
      u16* dst = (bn < 4) ? qbuf : kbuf;
      #pragma unroll
      for (int i = 0; i < 8; i++) {
        int chunk = i * 256 + tid;
        int r = chunk >> 4, c8 = chunk & 15;
        int nin = (bn & 3) * 128 + c8 * 8;
        int h = nin >> 6, d = nin & 63;
        uint4 val = *(const uint4*)&sm[r * 136 + c8 * 8];
        *(uint4*)&dst[(((size_t)(b * 8 + h)) * 1024 + nrow0 + r) * 64 + d] = val;
      }
    } else {
      #pragma unroll
      for (int i = 0; i < 8; i++) {
        int chunk = i * 256 + tid;
        int dcol = chunk & 127, nr8 = chunk >> 7;
        int nin = (bn & 3) * 128 + dcol;
        int h = nin >> 6, d = nin & 63;
        short8 v;
        #pragma unroll
        for (int j = 0; j < 8; j++) v[j] = (short)sm[(nr8 * 8 + j) * 136 + dcol];
        *(short8*)&vtbuf[(((size_t)(b * 8 + h)) * 64 + d) * 1024 + nrow0 + nr8 * 8] = v;
      }
    }
  } else {
    int t = (bid - 3072) * 256 + threadIdx.x;   // 1,048,576 threads
    int half = t & 1;
    int lane = (t >> 1) & 63;
    int ti   = (t >> 7) & 1;
    int w    = (t >> 8) & 3;
    int kt   = (t >> 10) & 15;
    int qt   = (t >> 14) & 7;
    int h    = t >> 17;
    int l15 = lane & 15, quad = lane >> 4;
    int qrow = qt * 128 + w * 32 + ti * 16 + l15;
    const int* rr = rel + (size_t)qrow * 1024 + kt * 64 + quad * 4;
    short8 o;
    #pragma unroll
    for (int j = 0; j < 2; j++) {
      int tjl = half * 2 + j;
      int4 idx = *(const int4*)&rr[tjl * 16];
      o[j * 4 + 0] = f2bf((tab[idx.x * 8 + h] - 8.0f) * 1.44269504f);
      o[j * 4 + 1] = f2bf((tab[idx.y * 8 + h] - 8.0f) * 1.44269504f);
      o[j * 4 + 2] = f2bf((tab[idx.z * 8 + h] - 8.0f) * 1.44269504f);
      o[j * 4 + 3] = f2bf((tab[idx.w * 8 + h] - 8.0f) * 1.44269504f);
    }
    ((short8*)biasb)[t] = o;
  }
}

// ---------------- flash attention v8 (verified R9): swapped QK^T, cheap pack -
// LDS (u16 idx): K0 [0,8192) V0 [8192,16384) K1 [16384,24576) V1 [24576,32768)
//                P [32768,40960)  (wave-private 32x64 per wave).
__global__ __launch_bounds__(256, 2) void k_attn(const u16* __restrict__ qbuf, const u16* __restrict__ kbuf,
                                                 const u16* __restrict__ vtbuf, const u16* __restrict__ biasb,
                                                 u16* __restrict__ attn_out) {
  __shared__ u16 sm[40960];
  const int PO = 32768;
  const int b = blockIdx.x, h = blockIdx.y >> 3, qt = blockIdx.y & 7;
  const int tid = threadIdx.x, w = tid >> 6, lane = tid & 63;
  const int quad = lane >> 4, l15 = lane & 15;
  const int xm = l15 & 7;
  const int qh = quad >> 1, ql = quad & 1;
  u16* pw = &sm[PO + w * 2048];                 // wave-private P: 32 rows x 64
  const size_t bh = (size_t)(b * 8 + h);
  const u16* qg = qbuf + (bh * 1024 + (size_t)qt * 128) * 64;
  const u16* kg = kbuf + bh * 1024 * 64;
  const u16* vg = vtbuf + bh * 64 * 1024;
  const u16* bg = biasb + (size_t)(h * 8 + qt) * 131072 + w * 2048 + lane * 16;

  // staging source indices (swizzled), loop-invariant (v4-identical)
  int rK[4], cK[4], dV[4], cV[4];
  #pragma unroll
  for (int i = 0; i < 4; i++) {
    int p = (w * 4 + i) * 64 + lane;
    rK[i] = p >> 3;  cK[i] = (p & 7) ^ (rK[i] & 7);
    dV[i] = p >> 4;  cV[i] = (p & 15) ^ (dV[i] & 7);
  }

  // Q fragments (MFMA B operand in swapped QK): once per block
  short8 qf[2][2];
  #pragma unroll
  for (int ti = 0; ti < 2; ti++)
    #pragma unroll
    for (int kk = 0; kk < 2; kk++)
      qf[ti][kk] = *(const short8*)&qg[(w * 32 + ti * 16 + l15) * 64 + kk * 32 + quad * 8];

  floatx4 oacc[2][4];
  floatx4 zero = {0.f, 0.f, 0.f, 0.f};
  #pragma unroll
  for (int i = 0; i < 2; i++)
    #pragma unroll
    for (int j = 0; j < 4; j++) oacc[i][j] = zero;
  float lrow[2] = {0.f, 0.f};   // partial row-sums, qrow = ti*16 + l15

  const float SC = 0.125f * 1.44269504f;

  // preload tile 0 into buffer 0 (v4-identical)
  #pragma unroll
  for (int i = 0; i < 4; i++) {
    gl_lds16(kg + (size_t)rK[i] * 64 + cK[i] * 8, &sm[(w * 4 + i) * 512]);
    gl_lds16(vg + (size_t)dV[i] * 1024 + cV[i] * 8, &sm[8192 + (w * 4 + i) * 512]);
  }
  __syncthreads();   // tile 0 resident

  for (int kt = 0; kt < 8; kt++) {
    const int cur = (kt & 1) ? 16384 : 0;
    const int nxt = (kt & 1) ? 0 : 16384;
    // prefetch kt+1 (v4-identical)
    if (kt < 7) {
      #pragma unroll
      for (int i = 0; i < 4; i++) {
        gl_lds16(kg + (size_t)((kt + 1) * 128 + rK[i]) * 64 + cK[i] * 8, &sm[nxt + (w * 4 + i) * 512]);
        gl_lds16(vg + (size_t)dV[i] * 1024 + (kt + 1) * 128 + cV[i] * 8, &sm[nxt + 8192 + (w * 4 + i) * 512]);
      }
    }

    #pragma unroll
    for (int tjh = 0; tjh < 2; tjh++) {
      // bias for this 64-col half (kt64 = kt*2 + tjh)
      const u16* bkt = bg + (kt * 2 + tjh) * 8192;
      const uint4 bA0 = *(const uint4*)&bkt[0];
      const uint4 bB0 = *(const uint4*)&bkt[8];
      const uint4 bA1 = *(const uint4*)&bkt[1024];
      const uint4 bB1 = *(const uint4*)&bkt[1024 + 8];

      // S^T = K Q^T for this 64-col half
      floatx4 sacc[2][4];
      #pragma unroll
      for (int tjl = 0; tjl < 4; tjl++) { sacc[0][tjl] = zero; sacc[1][tjl] = zero; }
      #pragma unroll
      for (int tjl = 0; tjl < 4; tjl++)
        #pragma unroll
        for (int kk = 0; kk < 2; kk++) {
          short8 kf = *(const short8*)&sm[cur + (tjh * 64 + tjl * 16 + l15) * 64 + ((kk * 4 + quad) ^ xm) * 8];
          sacc[0][tjl] = __builtin_amdgcn_mfma_f32_16x16x32_bf16(kf, qf[0][kk], sacc[0][tjl], 0, 0, 0);
          sacc[1][tjl] = __builtin_amdgcn_mfma_f32_16x16x32_bf16(kf, qf[1][kk], sacc[1][tjl], 0, 0, 0);
        }

      // softmax (static -8 shift, no max pass) + cheap half-up pack -> LDS
      #pragma unroll
      for (int ti = 0; ti < 2; ti++) {
        const uint4 bA = ti ? bA1 : bA0;
        const uint4 bB = ti ? bB1 : bB0;
        const int prow = (ti * 16 + l15) * 64;
        #pragma unroll
        for (int tjl = 0; tjl < 4; tjl++) {
          unsigned ulo = (tjl == 0) ? bA.x : (tjl == 1) ? bA.z : (tjl == 2) ? bB.x : bB.z;
          unsigned uhi = (tjl == 0) ? bA.y : (tjl == 1) ? bA.w : (tjl == 2) ? bB.y : bB.w;
          float b0 = __builtin_bit_cast(float, ulo << 16);
          float b1 = __builtin_bit_cast(float, ulo & 0xFFFF0000u);
          float b2 = __builtin_bit_cast(float, uhi << 16);
          float b3 = __builtin_bit_cast(float, uhi & 0xFFFF0000u);
          float p0 = exp2_fast(sacc[ti][tjl][0] * SC + b0);
          float p1 = exp2_fast(sacc[ti][tjl][1] * SC + b1);
          float p2 = exp2_fast(sacc[ti][tjl][2] * SC + b2);
          float p3 = exp2_fast(sacc[ti][tjl][3] * SC + b3);
          lrow[ti] += (p0 + p1) + (p2 + p3);
          s16x4 pv;
          pv[0] = (short)(u16)((__builtin_bit_cast(unsigned, p0) + 0x8000u) >> 16);
          pv[1] = (short)(u16)((__builtin_bit_cast(unsigned, p1) + 0x8000u) >> 16);
          pv[2] = (short)(u16)((__builtin_bit_cast(unsigned, p2) + 0x8000u) >> 16);
          pv[3] = (short)(u16)((__builtin_bit_cast(unsigned, p3) + 0x8000u) >> 16);
          *(s16x4*)&pw[prow + ((tjl * 2 + qh) ^ xm) * 8 + ql * 4] = pv;   // ds_write_b64
        }
      }
      // forbid compiler reordering of P reads before P writes (TBAA guard);
      // backend still inserts the lgkmcnt waits for the same-wave RAW.
      asm volatile("" ::: "memory");

      // O += P_half V_half   (V^T rows d=0..63, cols tjh*64 .. +63 of kt tile)
      #pragma unroll
      for (int kbl = 0; kbl < 2; kbl++) {
        const int gslP = ((kbl * 4 + quad) ^ xm) * 8;
        short8 pf0 = *(const short8*)&pw[l15 * 64 + gslP];
        short8 pf1 = *(const short8*)&pw[(16 + l15) * 64 + gslP];
        #pragma unroll
        for (int dj = 0; dj < 4; dj++) {
          int kc = (tjh * 8 + kbl * 4 + quad) ^ xm;   // V chunk (16 per row)
          short8 vf = *(const short8*)&sm[cur + 8192 + (dj * 16 + l15) * 128 + kc * 8];
          oacc[0][dj] = __builtin_amdgcn_mfma_f32_16x16x32_bf16(pf0, vf, oacc[0][dj], 0, 0, 0);
          oacc[1][dj] = __builtin_amdgcn_mfma_f32_16x16x32_bf16(pf1, vf, oacc[1][dj], 0, 0, 0);
        }
      }
    }
    __syncthreads();  // single barrier per kt: buffer handoff; vmcnt(0) drains
                      // a prefetch that aged through the whole compute phase
  }

  // epilogue: reduce row sums across quads, redistribute inv to O rows, store
  #pragma unroll
  for (int ti = 0; ti < 2; ti++) {
    float s = lrow[ti];
    s += __shfl_xor(s, 16);
    s += __shfl_xor(s, 32);
    float inv = 1.f / s;      // valid for qrow = ti*16 + l15
    #pragma unroll
    for (int r = 0; r < 4; r++) {
      float invr = __shfl(inv, (lane & 48) | (quad * 4 + r));  // inv of qrow quad*4+r
      int row = w * 32 + ti * 16 + quad * 4 + r;
      size_t ob = ((size_t)(b * 1024 + qt * 128 + row)) * 512 + h * 64;
      #pragma unroll
      for (int dj = 0; dj < 4; dj++)
        attn_out[ob + dj * 16 + l15] = f2bf(oacc[ti][dj][r] * invr);
    }
  }
}

// ---------------- GEMM3: out = attn @ w_out + b_out (fp32 out) ---------------
__global__ __launch_bounds__(256) void k_gemm_out(const u16* __restrict__ ab, const u16* __restrict__ wT,
                                                  const float* __restrict__ bout, float* __restrict__ out) {
  __shared__ u16 sm[8192];
  const int bn = blockIdx.x, bm = blockIdx.y;
  const int tid = threadIdx.x, w = tid >> 6, lane = tid & 63;
  const int quad = lane >> 4, l15 = lane & 15;
  const int wr = w >> 1, wc = w & 1;
  const u16* Ag = ab + (size_t)bm * 128 * 512;
  const u16* Bg = wT + (size_t)bn * 128 * 512;
  float bv[4];
  #pragma unroll
  for (int tj = 0; tj < 4; tj++) bv[tj] = bout[bn * 128 + wc * 64 + tj * 16 + l15];
  floatx4 acc[4][4];
  floatx4 zero = {0.f, 0.f, 0.f, 0.f};
  #pragma unroll
  for (int i = 0; i < 4; i++)
    #pragma unroll
    for (int j = 0; j < 4; j++) acc[i][j] = zero;

  for (int kb = 0; kb < 512; kb += 32) {
    __syncthreads();
    #pragma unroll
    for (int i = 0; i < 2; i++) {
      int c = w * 128 + i * 64 + lane;
      int row = c >> 2, col = (c & 3) * 8;
      gl_lds16(Ag + (size_t)row * 512 + kb + col, &sm[(w * 128 + i * 64) * 8]);
      gl_lds16(Bg + (size_t)row * 512 + kb + col, &sm[4096 + (w * 128 + i * 64) * 8]);
    }
    __syncthreads();
    short8 af[4], bf[4];
    #pragma unroll
    for (int ti = 0; ti < 4; ti++)
      af[ti] = *(const short8*)&sm[(wr * 64 + ti * 16 + l15) * 32 + quad * 8];
    #pragma unroll
    for (int tj = 0; tj < 4; tj++)
      bf[tj] = *(const short8*)&sm[4096 + (wc * 64 + tj * 16 + l15) * 32 + quad * 8];
    #pragma unroll
    for (int ti = 0; ti < 4; ti++)
      #pragma unroll
      for (int tj = 0; tj < 4; tj++)
        acc[ti][tj] = __builtin_amdgcn_mfma_f32_16x16x32_bf16(af[ti], bf[tj], acc[ti][tj], 0, 0, 0);
  }
  #pragma unroll
  for (int ti = 0; ti < 4; ti++)
    #pragma unroll
    for (int tj = 0; tj < 4; tj++)
      #pragma unroll
      for (int r = 0; r < 4; r++) {
        int row = bm * 128 + wr * 64 + ti * 16 + quad * 4 + r;
        int colg = bn * 128 + wc * 64 + tj * 16 + l15;
        out[(size_t)row * 512 + colg] = acc[ti][tj][r] + bv[tj];
      }
}

// ---------------- launch -----------------------------------------------------
extern "C" void kernel_launch(void* const* d_in, const int* in_sizes, int n_in,
                              void* d_out, int out_size, void* d_ws, size_t ws_size,
                              hipStream_t stream) {
  const float* x    = (const float*)d_in[0];
  const float* wqkv = (const float*)d_in[1];
  const float* wout = (const float*)d_in[2];
  const float* bout = (const float*)d_in[3];
  const float* btab = (const float*)d_in[4];
  const int*   rel  = (const int*)d_in[5];
  char* ws = (char*)d_ws;
  u16* xb    = (u16*)(ws + 0);           // x bf16, reused as attn_out
  u16* qbuf  = (u16*)(ws + 33554432);
  u16* kbuf  = (u16*)(ws + 67108864);
  u16* vtbuf = (u16*)(ws + 100663296);
  u16* biasb = (u16*)(ws + 134217728);
  u16* wqkvT = (u16*)(ws + 150994944);
  u16* woutT = (u16*)(ws + 152567808);
  float* out = (float*)d_out;

  k_prep          <<<12288, 256, 0, stream>>>(x, xb, wqkv, wout, wqkvT, woutT);
  k_gemm_qkv_bias <<<7168, 256, 0, stream>>>(xb, wqkvT, qbuf, kbuf, vtbuf, rel, btab, biasb);
  k_attn          <<<dim3(32, 64), 256, 0, stream>>>(qbuf, kbuf, vtbuf, biasb, xb);
  k_gemm_out      <<<dim3(4, 256), 256, 0, stream>>>(xb, woutT, bout, out);
}

// Round 11
// 365.358 us; speedup vs baseline: 1.0425x; 1.0038x over previous
//
#include <hip/hip_runtime.h>
#include <stdint.h>

typedef unsigned short u16;
typedef __attribute__((ext_vector_type(8))) short short8;   // 8 x bf16 (4 VGPRs)
typedef __attribute__((ext_vector_type(4))) short s16x4;    // 4 x bf16 (2 VGPRs)
typedef __attribute__((ext_vector_type(4))) float floatx4;  // MFMA 16x16 C/D

__device__ __forceinline__ u16 f2bf(float f) {
  union { float f; unsigned u; } v; v.f = f;
  return (u16)((v.u + 0x7FFFu + ((v.u >> 16) & 1u)) >> 16);  // RNE
}
__device__ __forceinline__ void gl_lds16(const void* g, void* l) {
  __builtin_amdgcn_global_load_lds((const __attribute__((address_space(1))) void*)g,
                                   (__attribute__((address_space(3))) void*)l, 16, 0, 0);
}
__device__ __forceinline__ float exp2_fast(float x) {
#if __has_builtin(__builtin_amdgcn_exp2f)
  return __builtin_amdgcn_exp2f(x);
#else
  return exp2f(x);
#endif
}

// ---------------- fused prep: cast x (blocks 0..8191) | transpose w (8192..) -
__global__ __launch_bounds__(256) void k_prep(const float* __restrict__ x, u16* __restrict__ xb,
                                              const float* __restrict__ wqkv, const float* __restrict__ wout,
                                              u16* __restrict__ wqkvT, u16* __restrict__ woutT) {
  int bid = blockIdx.x;
  if (bid < 8192) {
    int t = bid * 256 + threadIdx.x;
    const float4* xv = (const float4*)x;
    float4 a = xv[2 * t], b = xv[2 * t + 1];
    short8 o;
    o[0] = f2bf(a.x); o[1] = f2bf(a.y); o[2] = f2bf(a.z); o[3] = f2bf(a.w);
    o[4] = f2bf(b.x); o[5] = f2bf(b.y); o[6] = f2bf(b.z); o[7] = f2bf(b.w);
    ((short8*)xb)[t] = o;
  } else {
    int t = (bid - 8192) * 256 + threadIdx.x;
    if (t < 786432) {
      int n = t >> 9, k = t & 511;
      wqkvT[t] = f2bf(wqkv[k * 1536 + n]);
    } else {
      int u = t - 786432;
      int n = u >> 9, k = u & 511;
      woutT[u] = f2bf(wout[k * 512 + n]);
    }
  }
}

// ------ fused GEMM1 (blocks 0..3071, XCD-swizzled) | bias prep (3072..7167) --
// GEMM1: qkv = xb @ wqkvT^T -> Q,K [b,h,n,d], V^T [b,h,d,n].  XCD swizzle
// (T1): sw=(bid&7)*384+bid>>3 gives each XCD a contiguous bm range -> each
// 128KB A-tile is fetched into one XCD's L2 once (was ~8-12x across XCDs);
// B panel (1.5MB) stays L2-hot.  3072%8==0 -> bijective.  Bias prep is
// independent gather work co-resident to fill GEMM memory-wait bubbles.
__global__ __launch_bounds__(256) void k_gemm_qkv_bias(const u16* __restrict__ xb, const u16* __restrict__ wT,
                                                       u16* __restrict__ qbuf, u16* __restrict__ kbuf,
                                                       u16* __restrict__ vtbuf,
                                                       const int* __restrict__ rel, const float* __restrict__ tab,
                                                       u16* __restrict__ biasb) {
  __shared__ u16 sm[17408];
  const int bid = blockIdx.x;
  if (bid < 3072) {
    const int sw = (bid & 7) * 384 + (bid >> 3);
    const int bn = sw % 12, bm = sw / 12;
    const int tid = threadIdx.x, w = tid >> 6, lane = tid & 63;
    const int quad = lane >> 4, l15 = lane & 15;
    const int wr = w >> 1, wc = w & 1;
    const u16* Ag = xb + (size_t)bm * 128 * 512;
    const u16* Bg = wT + (size_t)bn * 128 * 512;
    floatx4 acc[4][4];
    floatx4 zero = {0.f, 0.f, 0.f, 0.f};
    #pragma unroll
    for (int i = 0; i < 4; i++)
      #pragma unroll
      for (int j = 0; j < 4; j++) acc[i][j] = zero;

    for (int kb = 0; kb < 512; kb += 32) {
      __syncthreads();
      #pragma unroll
      for (int i = 0; i < 2; i++) {
        int c = w * 128 + i * 64 + lane;
        int row = c >> 2, col = (c & 3) * 8;
        gl_lds16(Ag + (size_t)row * 512 + kb + col, &sm[(w * 128 + i * 64) * 8]);
        gl_lds16(Bg + (size_t)row * 512 + kb + col, &sm[4096 + (w * 128 + i * 64) * 8]);
      }
      __syncthreads();
      short8 af[4], bf[4];
      #pragma unroll
      for (int ti = 0; ti < 4; ti++)
        af[ti] = *(const short8*)&sm[(wr * 64 + ti * 16 + l15) * 32 + quad * 8];
      #pragma unroll
      for (int tj = 0; tj < 4; tj++)
        bf[tj] = *(const short8*)&sm[4096 + (wc * 64 + tj * 16 + l15) * 32 + quad * 8];
      #pragma unroll
      for (int ti = 0; ti < 4; ti++)
        #pragma unroll
        for (int tj = 0; tj < 4; tj++)
          acc[ti][tj] = __builtin_amdgcn_mfma_f32_16x16x32_bf16(af[ti], bf[tj], acc[ti][tj], 0, 0, 0);
    }
    __syncthreads();
    #pragma unroll
    for (int ti = 0; ti < 4; ti++)
      #pragma unroll
      for (int tj = 0; tj < 4; tj++)
        #pragma unroll
        for (int r = 0; r < 4; r++)
          sm[(wr * 64 + ti * 16 + quad * 4 + r) * 136 + wc * 64 + tj * 16 + l15] = f2bf(acc[ti][tj][r]);
    __syncthreads();
    const int b = bm >> 3;
    const int nrow0 = (bm & 7) * 128;
    if (bn < 8) {
      u16* dst = (bn < 4) ? qbuf : kbuf;
      #pragma unroll
      for (int i = 0; i < 8; i++) {
        int chunk = i * 256 + tid;
        int r = chunk >> 4, c8 = chunk & 15;
        int nin = (bn & 3) * 128 + c8 * 8;
        int h = nin >> 6, d = nin & 63;
        uint4 val = *(const uint4*)&sm[r * 136 + c8 * 8];
        *(uint4*)&dst[(((size_t)(b * 8 + h)) * 1024 + nrow0 + r) * 64 + d] = val;
      }
    } else {
      #pragma unroll
      for (int i = 0; i < 8; i++) {
        int chunk = i * 256 + tid;
        int dcol = chunk & 127, nr8 = chunk >> 7;
        int nin = (bn & 3) * 128 + dcol;
        int h = nin >> 6, d = nin & 63;
        short8 v;
        #pragma unroll
        for (int j = 0; j < 8; j++) v[j] = (short)sm[(nr8 * 8 + j) * 136 + dcol];
        *(short8*)&vtbuf[(((size_t)(b * 8 + h)) * 64 + d) * 1024 + nrow0 + nr8 * 8] = v;
      }
    }
  } else {
    int t = (bid - 3072) * 256 + threadIdx.x;   // 1,048,576 threads
    int half = t & 1;
    int lane = (t >> 1) & 63;
    int ti   = (t >> 7) & 1;
    int w    = (t >> 8) & 3;
    int kt   = (t >> 10) & 15;
    int qt   = (t >> 14) & 7;
    int h    = t >> 17;
    int l15 = lane & 15, quad = lane >> 4;
    int qrow = qt * 128 + w * 32 + ti * 16 + l15;
    const int* rr = rel + (size_t)qrow * 1024 + kt * 64 + quad * 4;
    short8 o;
    #pragma unroll
    for (int j = 0; j < 2; j++) {
      int tjl = half * 2 + j;
      int4 idx = *(const int4*)&rr[tjl * 16];
      o[j * 4 + 0] = f2bf((tab[idx.x * 8 + h] - 8.0f) * 1.44269504f);
      o[j * 4 + 1] = f2bf((tab[idx.y * 8 + h] - 8.0f) * 1.44269504f);
      o[j * 4 + 2] = f2bf((tab[idx.z * 8 + h] - 8.0f) * 1.44269504f);
      o[j * 4 + 3] = f2bf((tab[idx.w * 8 + h] - 8.0f) * 1.44269504f);
    }
    ((short8*)biasb)[t] = o;
  }
}

// ------- flash attention v9: v8 + MFMA rowsum (P x ones), shuffle-free -------
// Row-sum moved off the VALU (50% busy) onto the MFMA pipe (21%): a splat-1.0
// B-fragment gives D[i][j]=rowsum(P row i); C/D layout row=quad*4+r means each
// lane directly holds the inverse it needs in the epilogue (no shfl at all).
// Denominator now sums the bf16-rounded P -- self-consistent with the PV
// numerator.  -32 VALU adds/half, +4 MFMA/half, -lrow regs +8 acc regs.
// LDS (u16 idx): K0 [0,8192) V0 [8192,16384) K1 [16384,24576) V1 [24576,32768)
//                P [32768,40960)  (wave-private 32x64 per wave).
__global__ __launch_bounds__(256, 2) void k_attn(const u16* __restrict__ qbuf, const u16* __restrict__ kbuf,
                                                 const u16* __restrict__ vtbuf, const u16* __restrict__ biasb,
                                                 u16* __restrict__ attn_out) {
  __shared__ u16 sm[40960];
  const int PO = 32768;
  const int b = blockIdx.x, h = blockIdx.y >> 3, qt = blockIdx.y & 7;
  const int tid = threadIdx.x, w = tid >> 6, lane = tid & 63;
  const int quad = lane >> 4, l15 = lane & 15;
  const int xm = l15 & 7;
  const int qh = quad >> 1, ql = quad & 1;
  u16* pw = &sm[PO + w * 2048];                 // wave-private P: 32 rows x 64
  const size_t bh = (size_t)(b * 8 + h);
  const u16* qg = qbuf + (bh * 1024 + (size_t)qt * 128) * 64;
  const u16* kg = kbuf + bh * 1024 * 64;
  const u16* vg = vtbuf + bh * 64 * 1024;
  const u16* bg = biasb + (size_t)(h * 8 + qt) * 131072 + w * 2048 + lane * 16;

  // staging source indices (swizzled), loop-invariant (v4-identical)
  int rK[4], cK[4], dV[4], cV[4];
  #pragma unroll
  for (int i = 0; i < 4; i++) {
    int p = (w * 4 + i) * 64 + lane;
    rK[i] = p >> 3;  cK[i] = (p & 7) ^ (rK[i] & 7);
    dV[i] = p >> 4;  cV[i] = (p & 15) ^ (dV[i] & 7);
  }

  // Q fragments (MFMA B operand in swapped QK): once per block
  short8 qf[2][2];
  #pragma unroll
  for (int ti = 0; ti < 2; ti++)
    #pragma unroll
    for (int kk = 0; kk < 2; kk++)
      qf[ti][kk] = *(const short8*)&qg[(w * 32 + ti * 16 + l15) * 64 + kk * 32 + quad * 8];

  // all-ones bf16 B-fragment for the rowsum MFMA
  short8 onesf;
  #pragma unroll
  for (int j = 0; j < 8; j++) onesf[j] = (short)0x3F80;

  floatx4 oacc[2][4];
  floatx4 oaccS[2];
  floatx4 zero = {0.f, 0.f, 0.f, 0.f};
  #pragma unroll
  for (int i = 0; i < 2; i++) {
    #pragma unroll
    for (int j = 0; j < 4; j++) oacc[i][j] = zero;
    oaccS[i] = zero;
  }

  const float SC = 0.125f * 1.44269504f;

  // preload tile 0 into buffer 0 (v4-identical)
  #pragma unroll
  for (int i = 0; i < 4; i++) {
    gl_lds16(kg + (size_t)rK[i] * 64 + cK[i] * 8, &sm[(w * 4 + i) * 512]);
    gl_lds16(vg + (size_t)dV[i] * 1024 + cV[i] * 8, &sm[8192 + (w * 4 + i) * 512]);
  }
  __syncthreads();   // tile 0 resident

  for (int kt = 0; kt < 8; kt++) {
    const int cur = (kt & 1) ? 16384 : 0;
    const int nxt = (kt & 1) ? 0 : 16384;
    // prefetch kt+1 (v4-identical)
    if (kt < 7) {
      #pragma unroll
      for (int i = 0; i < 4; i++) {
        gl_lds16(kg + (size_t)((kt + 1) * 128 + rK[i]) * 64 + cK[i] * 8, &sm[nxt + (w * 4 + i) * 512]);
        gl_lds16(vg + (size_t)dV[i] * 1024 + (kt + 1) * 128 + cV[i] * 8, &sm[nxt + 8192 + (w * 4 + i) * 512]);
      }
    }

    #pragma unroll
    for (int tjh = 0; tjh < 2; tjh++) {
      // bias for this 64-col half (kt64 = kt*2 + tjh)
      const u16* bkt = bg + (kt * 2 + tjh) * 8192;
      const uint4 bA0 = *(const uint4*)&bkt[0];
      const uint4 bB0 = *(const uint4*)&bkt[8];
      const uint4 bA1 = *(const uint4*)&bkt[1024];
      const uint4 bB1 = *(const uint4*)&bkt[1024 + 8];

      // S^T = K Q^T for this 64-col half
      floatx4 sacc[2][4];
      #pragma unroll
      for (int tjl = 0; tjl < 4; tjl++) { sacc[0][tjl] = zero; sacc[1][tjl] = zero; }
      #pragma unroll
      for (int tjl = 0; tjl < 4; tjl++)
        #pragma unroll
        for (int kk = 0; kk < 2; kk++) {
          short8 kf = *(const short8*)&sm[cur + (tjh * 64 + tjl * 16 + l15) * 64 + ((kk * 4 + quad) ^ xm) * 8];
          sacc[0][tjl] = __builtin_amdgcn_mfma_f32_16x16x32_bf16(kf, qf[0][kk], sacc[0][tjl], 0, 0, 0);
          sacc[1][tjl] = __builtin_amdgcn_mfma_f32_16x16x32_bf16(kf, qf[1][kk], sacc[1][tjl], 0, 0, 0);
        }

      // softmax (static -8 shift, no max pass) + cheap half-up pack -> LDS
      #pragma unroll
      for (int ti = 0; ti < 2; ti++) {
        const uint4 bA = ti ? bA1 : bA0;
        const uint4 bB = ti ? bB1 : bB0;
        const int prow = (ti * 16 + l15) * 64;
        #pragma unroll
        for (int tjl = 0; tjl < 4; tjl++) {
          unsigned ulo = (tjl == 0) ? bA.x : (tjl == 1) ? bA.z : (tjl == 2) ? bB.x : bB.z;
          unsigned uhi = (tjl == 0) ? bA.y : (tjl == 1) ? bA.w : (tjl == 2) ? bB.y : bB.w;
          float b0 = __builtin_bit_cast(float, ulo << 16);
          float b1 = __builtin_bit_cast(float, ulo & 0xFFFF0000u);
          float b2 = __builtin_bit_cast(float, uhi << 16);
          float b3 = __builtin_bit_cast(float, uhi & 0xFFFF0000u);
          float p0 = exp2_fast(sacc[ti][tjl][0] * SC + b0);
          float p1 = exp2_fast(sacc[ti][tjl][1] * SC + b1);
          float p2 = exp2_fast(sacc[ti][tjl][2] * SC + b2);
          float p3 = exp2_fast(sacc[ti][tjl][3] * SC + b3);
          s16x4 pv;
          pv[0] = (short)(u16)((__builtin_bit_cast(unsigned, p0) + 0x8000u) >> 16);
          pv[1] = (short)(u16)((__builtin_bit_cast(unsigned, p1) + 0x8000u) >> 16);
          pv[2] = (short)(u16)((__builtin_bit_cast(unsigned, p2) + 0x8000u) >> 16);
          pv[3] = (short)(u16)((__builtin_bit_cast(unsigned, p3) + 0x8000u) >> 16);
          *(s16x4*)&pw[prow + ((tjl * 2 + qh) ^ xm) * 8 + ql * 4] = pv;   // ds_write_b64
        }
      }
      // forbid compiler reordering of P reads before P writes (TBAA guard);
      // backend still inserts the lgkmcnt waits for the same-wave RAW.
      asm volatile("" ::: "memory");

      // O += P_half V_half; rowsum += P_half x ones (MFMA pipe, no VALU)
      #pragma unroll
      for (int kbl = 0; kbl < 2; kbl++) {
        const int gslP = ((kbl * 4 + quad) ^ xm) * 8;
        short8 pf0 = *(const short8*)&pw[l15 * 64 + gslP];
        short8 pf1 = *(const short8*)&pw[(16 + l15) * 64 + gslP];
        oaccS[0] = __builtin_amdgcn_mfma_f32_16x16x32_bf16(pf0, onesf, oaccS[0], 0, 0, 0);
        oaccS[1] = __builtin_amdgcn_mfma_f32_16x16x32_bf16(pf1, onesf, oaccS[1], 0, 0, 0);
        #pragma unroll
        for (int dj = 0; dj < 4; dj++) {
          int kc = (tjh * 8 + kbl * 4 + quad) ^ xm;   // V chunk (16 per row)
          short8 vf = *(const short8*)&sm[cur + 8192 + (dj * 16 + l15) * 128 + kc * 8];
          oacc[0][dj] = __builtin_amdgcn_mfma_f32_16x16x32_bf16(pf0, vf, oacc[0][dj], 0, 0, 0);
          oacc[1][dj] = __builtin_amdgcn_mfma_f32_16x16x32_bf16(pf1, vf, oacc[1][dj], 0, 0, 0);
        }
      }
    }
    __syncthreads();  // single barrier per kt: buffer handoff; vmcnt(0) drains
                      // a prefetch that aged through the whole compute phase
  }

  // epilogue: oaccS[ti][r] = rowsum of qrow ti*16+quad*4+r -- shuffle-free
  #pragma unroll
  for (int ti = 0; ti < 2; ti++)
    #pragma unroll
    for (int r = 0; r < 4; r++) {
      float inv = 1.f / oaccS[ti][r];
      int row = w * 32 + ti * 16 + quad * 4 + r;
      size_t ob = ((size_t)(b * 1024 + qt * 128 + row)) * 512 + h * 64;
      #pragma unroll
      for (int dj = 0; dj < 4; dj++)
        attn_out[ob + dj * 16 + l15] = f2bf(oacc[ti][dj][r] * inv);
    }
}

// --------- GEMM3: out = attn @ w_out + b_out (fp32 out), XCD-swizzled --------
__global__ __launch_bounds__(256) void k_gemm_out(const u16* __restrict__ ab, const u16* __restrict__ wT,
                                                  const float* __restrict__ bout, float* __restrict__ out) {
  __shared__ u16 sm[8192];
  const int sw = (blockIdx.x & 7) * 128 + (blockIdx.x >> 3);   // 1024%8==0 bijective
  const int bn = sw & 3, bm = sw >> 2;
  const int tid = threadIdx.x, w = tid >> 6, lane = tid & 63;
  const int quad = lane >> 4, l15 = lane & 15;
  const int wr = w >> 1, wc = w & 1;
  const u16* Ag = ab + (size_t)bm * 128 * 512;
  const u16* Bg = wT + (size_t)bn * 128 * 512;
  float bv[4];
  #pragma unroll
  for (int tj = 0; tj < 4; tj++) bv[tj] = bout[bn * 128 + wc * 64 + tj * 16 + l15];
  floatx4 acc[4][4];
  floatx4 zero = {0.f, 0.f, 0.f, 0.f};
  #pragma unroll
  for (int i = 0; i < 4; i++)
    #pragma unroll
    for (int j = 0; j < 4; j++) acc[i][j] = zero;

  for (int kb = 0; kb < 512; kb += 32) {
    __syncthreads();
    #pragma unroll
    for (int i = 0; i < 2; i++) {
      int c = w * 128 + i * 64 + lane;
      int row = c >> 2, col = (c & 3) * 8;
      gl_lds16(Ag + (size_t)row * 512 + kb + col, &sm[(w * 128 + i * 64) * 8]);
      gl_lds16(Bg + (size_t)row * 512 + kb + col, &sm[4096 + (w * 128 + i * 64) * 8]);
    }
    __syncthreads();
    short8 af[4], bf[4];
    #pragma unroll
    for (int ti = 0; ti < 4; ti++)
      af[ti] = *(const short8*)&sm[(wr * 64 + ti * 16 + l15) * 32 + quad * 8];
    #pragma unroll
    for (int tj = 0; tj < 4; tj++)
      bf[tj] = *(const short8*)&sm[4096 + (wc * 64 + tj * 16 + l15) * 32 + quad * 8];
    #pragma unroll
    for (int ti = 0; ti < 4; ti++)
      #pragma unroll
      for (int tj = 0; tj < 4; tj++)
        acc[ti][tj] = __builtin_amdgcn_mfma_f32_16x16x32_bf16(af[ti], bf[tj], acc[ti][tj], 0, 0, 0);
  }
  #pragma unroll
  for (int ti = 0; ti < 4; ti++)
    #pragma unroll
    for (int tj = 0; tj < 4; tj++)
      #pragma unroll
      for (int r = 0; r < 4; r++) {
        int row = bm * 128 + wr * 64 + ti * 16 + quad * 4 + r;
        int colg = bn * 128 + wc * 64 + tj * 16 + l15;
        out[(size_t)row * 512 + colg] = acc[ti][tj][r] + bv[tj];
      }
}

// ---------------- launch -----------------------------------------------------
extern "C" void kernel_launch(void* const* d_in, const int* in_sizes, int n_in,
                              void* d_out, int out_size, void* d_ws, size_t ws_size,
                              hipStream_t stream) {
  const float* x    = (const float*)d_in[0];
  const float* wqkv = (const float*)d_in[1];
  const float* wout = (const float*)d_in[2];
  const float* bout = (const float*)d_in[3];
  const float* btab = (const float*)d_in[4];
  const int*   rel  = (const int*)d_in[5];
  char* ws = (char*)d_ws;
  u16* xb    = (u16*)(ws + 0);           // x bf16, reused as attn_out
  u16* qbuf  = (u16*)(ws + 33554432);
  u16* kbuf  = (u16*)(ws + 67108864);
  u16* vtbuf = (u16*)(ws + 100663296);
  u16* biasb = (u16*)(ws + 134217728);
  u16* wqkvT = (u16*)(ws + 150994944);
  u16* woutT = (u16*)(ws + 152567808);
  float* out = (float*)d_out;

  k_prep          <<<12288, 256, 0, stream>>>(x, xb, wqkv, wout, wqkvT, woutT);
  k_gemm_qkv_bias <<<7168, 256, 0, stream>>>(xb, wqkvT, qbuf, kbuf, vtbuf, rel, btab, biasb);
  k_attn          <<<dim3(32, 64), 256, 0, stream>>>(qbuf, kbuf, vtbuf, biasb, xb);
  k_gemm_out      <<<1024, 256, 0, stream>>>(xb, woutT, bout, out);
}

// Round 14
// 341.037 us; speedup vs baseline: 1.1169x; 1.0713x over previous
//
#include <hip/hip_runtime.h>
#include <stdint.h>

typedef unsigned short u16;
typedef __attribute__((ext_vector_type(8))) short short8;   // 8 x bf16 (4 VGPRs)
typedef __attribute__((ext_vector_type(4))) short s16x4;    // 4 x bf16 (2 VGPRs)
typedef __attribute__((ext_vector_type(4))) float floatx4;  // MFMA 16x16 C/D

__device__ __forceinline__ u16 f2bf(float f) {
  union { float f; unsigned u; } v; v.f = f;
  return (u16)((v.u + 0x7FFFu + ((v.u >> 16) & 1u)) >> 16);  // RNE
}
__device__ __forceinline__ void gl_lds16(const void* g, void* l) {
  __builtin_amdgcn_global_load_lds((const __attribute__((address_space(1))) void*)g,
                                   (__attribute__((address_space(3))) void*)l, 16, 0, 0);
}
__device__ __forceinline__ float exp2_fast(float x) {
#if __has_builtin(__builtin_amdgcn_exp2f)
  return __builtin_amdgcn_exp2f(x);
#else
  return exp2f(x);
#endif
}

// ---------------- fused prep: cast x (blocks 0..8191) | transpose w (8192..) -
__global__ __launch_bounds__(256) void k_prep(const float* __restrict__ x, u16* __restrict__ xb,
                                              const float* __restrict__ wqkv, const float* __restrict__ wout,
                                              u16* __restrict__ wqkvT, u16* __restrict__ woutT) {
  int bid = blockIdx.x;
  if (bid < 8192) {
    int t = bid * 256 + threadIdx.x;
    const float4* xv = (const float4*)x;
    float4 a = xv[2 * t], b = xv[2 * t + 1];
    short8 o;
    o[0] = f2bf(a.x); o[1] = f2bf(a.y); o[2] = f2bf(a.z); o[3] = f2bf(a.w);
    o[4] = f2bf(b.x); o[5] = f2bf(b.y); o[6] = f2bf(b.z); o[7] = f2bf(b.w);
    ((short8*)xb)[t] = o;
  } else {
    int t = (bid - 8192) * 256 + threadIdx.x;
    if (t < 786432) {
      int n = t >> 9, k = t & 511;
      wqkvT[t] = f2bf(wqkv[k * 1536 + n]);
    } else {
      int u = t - 786432;
      int n = u >> 9, k = u & 511;
      woutT[u] = f2bf(wout[k * 512 + n]);
    }
  }
}

// ------ fused GEMM1 | bias prep, INTERLEAVED in block-ID space ---------------
// 7168 blocks = 1024 groups x 7: per group 3 GEMM + 4 bias (3072 + 4096,
// bijective).  R10 appended bias AFTER the GEMM ids, so ~8 dispatch rounds of
// latency-bound bias gather ran serially after the GEMM; interleaving makes
// both types co-resident for the whole dispatch -> gather hides in GEMM
// stall bubbles.  GEMM keeps the T1 XCD swizzle on its own index space.
__global__ __launch_bounds__(256) void k_gemm_qkv_bias(const u16* __restrict__ xb, const u16* __restrict__ wT,
                                                       u16* __restrict__ qbuf, u16* __restrict__ kbuf,
                                                       u16* __restrict__ vtbuf,
                                                       const int* __restrict__ rel, const float* __restrict__ tab,
                                                       u16* __restrict__ biasb) {
  __shared__ u16 sm[17408];
  const int bid = blockIdx.x;
  const int g = bid / 7, r7 = bid % 7;
  if (r7 < 3) {
    const int gi = g * 3 + r7;                      // [0, 3072)
    const int sw = (gi & 7) * 384 + (gi >> 3);      // XCD swizzle, bijective
    const int bn = sw % 12, bm = sw / 12;
    const int tid = threadIdx.x, w = tid >> 6, lane = tid & 63;
    const int quad = lane >> 4, l15 = lane & 15;
    const int wr = w >> 1, wc = w & 1;
    const u16* Ag = xb + (size_t)bm * 128 * 512;
    const u16* Bg = wT + (size_t)bn * 128 * 512;
    floatx4 acc[4][4];
    floatx4 zero = {0.f, 0.f, 0.f, 0.f};
    #pragma unroll
    for (int i = 0; i < 4; i++)
      #pragma unroll
      for (int j = 0; j < 4; j++) acc[i][j] = zero;

    for (int kb = 0; kb < 512; kb += 32) {
      __syncthreads();
      #pragma unroll
      for (int i = 0; i < 2; i++) {
        int c = w * 128 + i * 64 + lane;
        int row = c >> 2, col = (c & 3) * 8;
        gl_lds16(Ag + (size_t)row * 512 + kb + col, &sm[(w * 128 + i * 64) * 8]);
        gl_lds16(Bg + (size_t)row * 512 + kb + col, &sm[4096 + (w * 128 + i * 64) * 8]);
      }
      __syncthreads();
      short8 af[4], bf[4];
      #pragma unroll
      for (int ti = 0; ti < 4; ti++)
        af[ti] = *(const short8*)&sm[(wr * 64 + ti * 16 + l15) * 32 + quad * 8];
      #pragma unroll
      for (int tj = 0; tj < 4; tj++)
        bf[tj] = *(const short8*)&sm[4096 + (wc * 64 + tj * 16 + l15) * 32 + quad * 8];
      #pragma unroll
      for (int ti = 0; ti < 4; ti++)
        #pragma unroll
        for (int tj = 0; tj < 4; tj++)
          acc[ti][tj] = __builtin_amdgcn_mfma_f32_16x16x32_bf16(af[ti], bf[tj], acc[ti][tj], 0, 0, 0);
    }
    __syncthreads();
    #pragma unroll
    for (int ti = 0; ti < 4; ti++)
      #pragma unroll
      for (int tj = 0; tj < 4; tj++)
        #pragma unroll
        for (int r = 0; r < 4; r++)
          sm[(wr * 64 + ti * 16 + quad * 4 + r) * 136 + wc * 64 + tj * 16 + l15] = f2bf(acc[ti][tj][r]);
    __syncthreads();
    const int b = bm >> 3;
    const int nrow0 = (bm & 7) * 128;
    if (bn < 8) {
      u16* dst = (bn < 4) ? qbuf : kbuf;
      #pragma unroll
      for (int i = 0; i < 8; i++) {
        int chunk = i * 256 + tid;
        int r = chunk >> 4, c8 = chunk & 15;
        int nin = (bn & 3) * 128 + c8 * 8;
        int h = nin >> 6, d = nin & 63;
        uint4 val = *(const uint4*)&sm[r * 136 + c8 * 8];
        *(uint4*)&dst[(((size_t)(b * 8 + h)) * 1024 + nrow0 + r) * 64 + d] = val;
      }
    } else {
      #pragma unroll
      for (int i = 0; i < 8; i++) {
        int chunk = i * 256 + tid;
        int dcol = chunk & 127, nr8 = chunk >> 7;
        int nin = (bn & 3) * 128 + dcol;
        int h = nin >> 6, d = nin & 63;
        short8 v;
        #pragma unroll
        for (int j = 0; j < 8; j++) v[j] = (short)sm[(nr8 * 8 + j) * 136 + dcol];
        *(short8*)&vtbuf[(((size_t)(b * 8 + h)) * 64 + d) * 1024 + nrow0 + nr8 * 8] = v;
      }
    }
  } else {
    int t = (g * 4 + (r7 - 3)) * 256 + threadIdx.x;   // bias idx [0,4096) -> 1,048,576 threads
    int half = t & 1;
    int lane = (t >> 1) & 63;
    int ti   = (t >> 7) & 1;
    int w    = (t >> 8) & 3;
    int kt   = (t >> 10) & 15;
    int qt   = (t >> 14) & 7;
    int h    = t >> 17;
    int l15 = lane & 15, quad = lane >> 4;
    int qrow = qt * 128 + w * 32 + ti * 16 + l15;
    const int* rr = rel + (size_t)qrow * 1024 + kt * 64 + quad * 4;
    short8 o;
    #pragma unroll
    for (int j = 0; j < 2; j++) {
      int tjl = half * 2 + j;
      int4 idx = *(const int4*)&rr[tjl * 16];
      o[j * 4 + 0] = f2bf((tab[idx.x * 8 + h] - 8.0f) * 1.44269504f);
      o[j * 4 + 1] = f2bf((tab[idx.y * 8 + h] - 8.0f) * 1.44269504f);
      o[j * 4 + 2] = f2bf((tab[idx.z * 8 + h] - 8.0f) * 1.44269504f);
      o[j * 4 + 3] = f2bf((tab[idx.w * 8 + h] - 8.0f) * 1.44269504f);
    }
    ((short8*)biasb)[t] = o;
  }
}

// ------- flash attention v10: v9 + both halves' bias loads hoisted to kt top -
// The asm memory fence after P-write(h0) was pinning tjh=1's bias loads below
// it -> issued at PV(h0), used one QK later (~150cy aging, < L2/L3 latency).
// Loading both halves at kt top gives the h1 set the whole h0 phase (~5K cy)
// to age.  +16 VGPR (4 extra uint4), budget 256/wave at 2 blocks/CU.
// LDS (u16 idx): K0 [0,8192) V0 [8192,16384) K1 [16384,24576) V1 [24576,32768)
//                P [32768,40960)  (wave-private 32x64 per wave).
__global__ __launch_bounds__(256, 2) void k_attn(const u16* __restrict__ qbuf, const u16* __restrict__ kbuf,
                                                 const u16* __restrict__ vtbuf, const u16* __restrict__ biasb,
                                                 u16* __restrict__ attn_out) {
  __shared__ u16 sm[40960];
  const int PO = 32768;
  const int b = blockIdx.x, h = blockIdx.y >> 3, qt = blockIdx.y & 7;
  const int tid = threadIdx.x, w = tid >> 6, lane = tid & 63;
  const int quad = lane >> 4, l15 = lane & 15;
  const int xm = l15 & 7;
  const int qh = quad >> 1, ql = quad & 1;
  u16* pw = &sm[PO + w * 2048];                 // wave-private P: 32 rows x 64
  const size_t bh = (size_t)(b * 8 + h);
  const u16* qg = qbuf + (bh * 1024 + (size_t)qt * 128) * 64;
  const u16* kg = kbuf + bh * 1024 * 64;
  const u16* vg = vtbuf + bh * 64 * 1024;
  const u16* bg = biasb + (size_t)(h * 8 + qt) * 131072 + w * 2048 + lane * 16;

  // staging source indices (swizzled), loop-invariant (v4-identical)
  int rK[4], cK[4], dV[4], cV[4];
  #pragma unroll
  for (int i = 0; i < 4; i++) {
    int p = (w * 4 + i) * 64 + lane;
    rK[i] = p >> 3;  cK[i] = (p & 7) ^ (rK[i] & 7);
    dV[i] = p >> 4;  cV[i] = (p & 15) ^ (dV[i] & 7);
  }

  // Q fragments (MFMA B operand in swapped QK): once per block
  short8 qf[2][2];
  #pragma unroll
  for (int ti = 0; ti < 2; ti++)
    #pragma unroll
    for (int kk = 0; kk < 2; kk++)
      qf[ti][kk] = *(const short8*)&qg[(w * 32 + ti * 16 + l15) * 64 + kk * 32 + quad * 8];

  // all-ones bf16 B-fragment for the rowsum MFMA
  short8 onesf;
  #pragma unroll
  for (int j = 0; j < 8; j++) onesf[j] = (short)0x3F80;

  floatx4 oacc[2][4];
  floatx4 oaccS[2];
  floatx4 zero = {0.f, 0.f, 0.f, 0.f};
  #pragma unroll
  for (int i = 0; i < 2; i++) {
    #pragma unroll
    for (int j = 0; j < 4; j++) oacc[i][j] = zero;
    oaccS[i] = zero;
  }

  const float SC = 0.125f * 1.44269504f;

  // preload tile 0 into buffer 0 (v4-identical)
  #pragma unroll
  for (int i = 0; i < 4; i++) {
    gl_lds16(kg + (size_t)rK[i] * 64 + cK[i] * 8, &sm[(w * 4 + i) * 512]);
    gl_lds16(vg + (size_t)dV[i] * 1024 + cV[i] * 8, &sm[8192 + (w * 4 + i) * 512]);
  }
  __syncthreads();   // tile 0 resident

  for (int kt = 0; kt < 8; kt++) {
    const int cur = (kt & 1) ? 16384 : 0;
    const int nxt = (kt & 1) ? 0 : 16384;
    // prefetch kt+1 (v4-identical)
    if (kt < 7) {
      #pragma unroll
      for (int i = 0; i < 4; i++) {
        gl_lds16(kg + (size_t)((kt + 1) * 128 + rK[i]) * 64 + cK[i] * 8, &sm[nxt + (w * 4 + i) * 512]);
        gl_lds16(vg + (size_t)dV[i] * 1024 + (kt + 1) * 128 + cV[i] * 8, &sm[nxt + 8192 + (w * 4 + i) * 512]);
      }
    }

    // bias for BOTH 64-col halves, issued at kt top (before any fence)
    const u16* bkt = bg + (kt * 2) * 8192;
    uint4 bb[2][4];
    #pragma unroll
    for (int th = 0; th < 2; th++) {
      bb[th][0] = *(const uint4*)&bkt[th * 8192 + 0];
      bb[th][1] = *(const uint4*)&bkt[th * 8192 + 8];
      bb[th][2] = *(const uint4*)&bkt[th * 8192 + 1024];
      bb[th][3] = *(const uint4*)&bkt[th * 8192 + 1024 + 8];
    }

    #pragma unroll
    for (int tjh = 0; tjh < 2; tjh++) {
      const uint4 bA0 = bb[tjh][0];
      const uint4 bB0 = bb[tjh][1];
      const uint4 bA1 = bb[tjh][2];
      const uint4 bB1 = bb[tjh][3];

      // S^T = K Q^T for this 64-col half
      floatx4 sacc[2][4];
      #pragma unroll
      for (int tjl = 0; tjl < 4; tjl++) { sacc[0][tjl] = zero; sacc[1][tjl] = zero; }
      #pragma unroll
      for (int tjl = 0; tjl < 4; tjl++)
        #pragma unroll
        for (int kk = 0; kk < 2; kk++) {
          short8 kf = *(const short8*)&sm[cur + (tjh * 64 + tjl * 16 + l15) * 64 + ((kk * 4 + quad) ^ xm) * 8];
          sacc[0][tjl] = __builtin_amdgcn_mfma_f32_16x16x32_bf16(kf, qf[0][kk], sacc[0][tjl], 0, 0, 0);
          sacc[1][tjl] = __builtin_amdgcn_mfma_f32_16x16x32_bf16(kf, qf[1][kk], sacc[1][tjl], 0, 0, 0);
        }

      // softmax (static -8 shift, no max pass) + cheap half-up pack -> LDS
      #pragma unroll
      for (int ti = 0; ti < 2; ti++) {
        const uint4 bA = ti ? bA1 : bA0;
        const uint4 bB = ti ? bB1 : bB0;
        const int prow = (ti * 16 + l15) * 64;
        #pragma unroll
        for (int tjl = 0; tjl < 4; tjl++) {
          unsigned ulo = (tjl == 0) ? bA.x : (tjl == 1) ? bA.z : (tjl == 2) ? bB.x : bB.z;
          unsigned uhi = (tjl == 0) ? bA.y : (tjl == 1) ? bA.w : (tjl == 2) ? bB.y : bB.w;
          float b0 = __builtin_bit_cast(float, ulo << 16);
          float b1 = __builtin_bit_cast(float, ulo & 0xFFFF0000u);
          float b2 = __builtin_bit_cast(float, uhi << 16);
          float b3 = __builtin_bit_cast(float, uhi & 0xFFFF0000u);
          float p0 = exp2_fast(sacc[ti][tjl][0] * SC + b0);
          float p1 = exp2_fast(sacc[ti][tjl][1] * SC + b1);
          float p2 = exp2_fast(sacc[ti][tjl][2] * SC + b2);
          float p3 = exp2_fast(sacc[ti][tjl][3] * SC + b3);
          s16x4 pv;
          pv[0] = (short)(u16)((__builtin_bit_cast(unsigned, p0) + 0x8000u) >> 16);
          pv[1] = (short)(u16)((__builtin_bit_cast(unsigned, p1) + 0x8000u) >> 16);
          pv[2] = (short)(u16)((__builtin_bit_cast(unsigned, p2) + 0x8000u) >> 16);
          pv[3] = (short)(u16)((__builtin_bit_cast(unsigned, p3) + 0x8000u) >> 16);
          *(s16x4*)&pw[prow + ((tjl * 2 + qh) ^ xm) * 8 + ql * 4] = pv;   // ds_write_b64
        }
      }
      // forbid compiler reordering of P reads before P writes (TBAA guard);
      // backend still inserts the lgkmcnt waits for the same-wave RAW.
      asm volatile("" ::: "memory");

      // O += P_half V_half; rowsum += P_half x ones (MFMA pipe, no VALU)
      #pragma unroll
      for (int kbl = 0; kbl < 2; kbl++) {
        const int gslP = ((kbl * 4 + quad) ^ xm) * 8;
        short8 pf0 = *(const short8*)&pw[l15 * 64 + gslP];
        short8 pf1 = *(const short8*)&pw[(16 + l15) * 64 + gslP];
        oaccS[0] = __builtin_amdgcn_mfma_f32_16x16x32_bf16(pf0, onesf, oaccS[0], 0, 0, 0);
        oaccS[1] = __builtin_amdgcn_mfma_f32_16x16x32_bf16(pf1, onesf, oaccS[1], 0, 0, 0);
        #pragma unroll
        for (int dj = 0; dj < 4; dj++) {
          int kc = (tjh * 8 + kbl * 4 + quad) ^ xm;   // V chunk (16 per row)
          short8 vf = *(const short8*)&sm[cur + 8192 + (dj * 16 + l15) * 128 + kc * 8];
          oacc[0][dj] = __builtin_amdgcn_mfma_f32_16x16x32_bf16(pf0, vf, oacc[0][dj], 0, 0, 0);
          oacc[1][dj] = __builtin_amdgcn_mfma_f32_16x16x32_bf16(pf1, vf, oacc[1][dj], 0, 0, 0);
        }
      }
    }
    __syncthreads();  // single barrier per kt: buffer handoff; vmcnt(0) drains
                      // a prefetch that aged through the whole compute phase
  }

  // epilogue: oaccS[ti][r] = rowsum of qrow ti*16+quad*4+r -- shuffle-free
  #pragma unroll
  for (int ti = 0; ti < 2; ti++)
    #pragma unroll
    for (int r = 0; r < 4; r++) {
      float inv = 1.f / oaccS[ti][r];
      int row = w * 32 + ti * 16 + quad * 4 + r;
      size_t ob = ((size_t)(b * 1024 + qt * 128 + row)) * 512 + h * 64;
      #pragma unroll
      for (int dj = 0; dj < 4; dj++)
        attn_out[ob + dj * 16 + l15] = f2bf(oacc[ti][dj][r] * inv);
    }
}

// --------- GEMM3: out = attn @ w_out + b_out (fp32 out), XCD-swizzled --------
__global__ __launch_bounds__(256) void k_gemm_out(const u16* __restrict__ ab, const u16* __restrict__ wT,
                                                  const float* __restrict__ bout, float* __restrict__ out) {
  __shared__ u16 sm[8192];
  const int sw = (blockIdx.x & 7) * 128 + (blockIdx.x >> 3);   // 1024%8==0 bijective
  const int bn = sw & 3, bm = sw >> 2;
  const int tid = threadIdx.x, w = tid >> 6, lane = tid & 63;
  const int quad = lane >> 4, l15 = lane & 15;
  const int wr = w >> 1, wc = w & 1;
  const u16* Ag = ab + (size_t)bm * 128 * 512;
  const u16* Bg = wT + (size_t)bn * 128 * 512;
  float bv[4];
  #pragma unroll
  for (int tj = 0; tj < 4; tj++) bv[tj] = bout[bn * 128 + wc * 64 + tj * 16 + l15];
  floatx4 acc[4][4];
  floatx4 zero = {0.f, 0.f, 0.f, 0.f};
  #pragma unroll
  for (int i = 0; i < 4; i++)
    #pragma unroll
    for (int j = 0; j < 4; j++) acc[i][j] = zero;

  for (int kb = 0; kb < 512; kb += 32) {
    __syncthreads();
    #pragma unroll
    for (int i = 0; i < 2; i++) {
      int c = w * 128 + i * 64 + lane;
      int row = c >> 2, col = (c & 3) * 8;
      gl_lds16(Ag + (size_t)row * 512 + kb + col, &sm[(w * 128 + i * 64) * 8]);
      gl_lds16(Bg + (size_t)row * 512 + kb + col, &sm[4096 + (w * 128 + i * 64) * 8]);
    }
    __syncthreads();
    short8 af[4], bf[4];
    #pragma unroll
    for (int ti = 0; ti < 4; ti++)
      af[ti] = *(const short8*)&sm[(wr * 64 + ti * 16 + l15) * 32 + quad * 8];
    #pragma unroll
    for (int tj = 0; tj < 4; tj++)
      bf[tj] = *(const short8*)&sm[4096 + (wc * 64 + tj * 16 + l15) * 32 + quad * 8];
    #pragma unroll
    for (int ti = 0; ti < 4; ti++)
      #pragma unroll
      for (int tj = 0; tj < 4; tj++)
        acc[ti][tj] = __builtin_amdgcn_mfma_f32_16x16x32_bf16(af[ti], bf[tj], acc[ti][tj], 0, 0, 0);
  }
  #pragma unroll
  for (int ti = 0; ti < 4; ti++)
    #pragma unroll
    for (int tj = 0; tj < 4; tj++)
      #pragma unroll
      for (int r = 0; r < 4; r++) {
        int row = bm * 128 + wr * 64 + ti * 16 + quad * 4 + r;
        int colg = bn * 128 + wc * 64 + tj * 16 + l15;
        out[(size_t)row * 512 + colg] = acc[ti][tj][r] + bv[tj];
      }
}

// ---------------- launch -----------------------------------------------------
extern "C" void kernel_launch(void* const* d_in, const int* in_sizes, int n_in,
                              void* d_out, int out_size, void* d_ws, size_t ws_size,
                              hipStream_t stream) {
  const float* x    = (const float*)d_in[0];
  const float* wqkv = (const float*)d_in[1];
  const float* wout = (const float*)d_in[2];
  const float* bout = (const float*)d_in[3];
  const float* btab = (const float*)d_in[4];
  const int*   rel  = (const int*)d_in[5];
  char* ws = (char*)d_ws;
  u16* xb    = (u16*)(ws + 0);           // x bf16, reused as attn_out
  u16* qbuf  = (u16*)(ws + 33554432);
  u16* kbuf  = (u16*)(ws + 67108864);
  u16* vtbuf = (u16*)(ws + 100663296);
  u16* biasb = (u16*)(ws + 134217728);
  u16* wqkvT = (u16*)(ws + 150994944);
  u16* woutT = (u16*)(ws + 152567808);
  float* out = (float*)d_out;

  k_prep          <<<12288, 256, 0, stream>>>(x, xb, wqkv, wout, wqkvT, woutT);
  k_gemm_qkv_bias <<<7168, 256, 0, stream>>>(xb, wqkvT, qbuf, kbuf, vtbuf, rel, btab, biasb);
  k_attn          <<<dim3(32, 64), 256, 0, stream>>>(qbuf, kbuf, vtbuf, biasb, xb);
  k_gemm_out      <<<1024, 256, 0, stream>>>(xb, woutT, bout, out);
}